// Round 10
// baseline (349.212 us; speedup 1.0000x reference)
//
#include <hip/hip_runtime.h>
#include <hip/hip_bf16.h>
#include <math.h>

#define NN 2048
#define CC 512
#define NEDGE 65536

typedef __hip_bfloat16 bf16;
typedef __attribute__((ext_vector_type(8))) short short8;
typedef __attribute__((ext_vector_type(4))) float floatx4;

static constexpr float TWO_PI_F = 6.2831853071795864769f;

// async global->LDS direct copy, 16 B per lane (dest = wave-uniform base + lane*16)
__device__ __forceinline__ void gld16(const void* g, void* l) {
    __builtin_amdgcn_global_load_lds(
        (const __attribute__((address_space(1))) unsigned int*)(unsigned long long)(uintptr_t)g,
        (__attribute__((address_space(3))) unsigned int*)(unsigned long long)(uintptr_t)l,
        16, 0, 0);
}

// ---------------- dtype-mode detector ----------------
__global__ void detect_k(const unsigned int* __restrict__ qword,
                         const unsigned int* __restrict__ ewords,
                         int* __restrict__ flag) {
    int lane = threadIdx.x;           // 64 threads
    unsigned int w0 = ewords[2 * lane + 1];
    unsigned int w1 = ewords[128 + 2 * lane + 1];
    unsigned long long b = __ballot((w0 | w1) != 0u);
    if (lane == 0) {
        flag[0] = ((qword[0] & 0xFFFFu) == 0x3E80u) ? 1 : 0;   // bf16 mode
        flag[1] = (b == 0ull) ? 1 : 0;                          // int64 edges
    }
}

// ---------------- prep kernels ----------------

__global__ void scatter_edges_k(const void* __restrict__ edges,
                                const void* __restrict__ w,
                                float* __restrict__ A,
                                const int* __restrict__ flag) {
    int e = blockIdx.x * 256 + threadIdx.x;
    if (e >= NEDGE) return;
    int f, t;
    if (flag[1]) {
        f = (int)((const long long*)edges)[e];
        t = (int)((const long long*)edges)[NEDGE + e];
    } else {
        f = ((const int*)edges)[e];
        t = ((const int*)edges)[NEDGE + e];
    }
    float wv = flag[0] ? __bfloat162float(((const bf16*)w)[e]) : ((const float*)w)[e];
    f &= (NN - 1); t &= (NN - 1);
    atomicAdd(&A[(size_t)f * NN + t], wv);
}

__global__ void row_sums_k(const float* __restrict__ A, float* __restrict__ rowsum) {
    int i = blockIdx.x;
    float s = 0.f;
    for (int j = threadIdx.x; j < NN; j += 256) s += A[(size_t)i * NN + j];
    __shared__ float red[256];
    red[threadIdx.x] = s;
    __syncthreads();
    for (int off = 128; off > 0; off >>= 1) {
        if (threadIdx.x < off) red[threadIdx.x] += red[threadIdx.x + off];
        __syncthreads();
    }
    if (threadIdx.x == 0) rowsum[i] = red[0];
}

__global__ void col_sums_k(const float* __restrict__ A, float* __restrict__ colsum) {
    int col = blockIdx.x * 256 + threadIdx.x;
    int r0 = blockIdx.y * 64;
    float s = 0.f;
    for (int r = r0; r < r0 + 64; ++r) s += A[(size_t)r * NN + col];
    atomicAdd(&colsum[col], s);
}

__global__ void dinv_k(const float* __restrict__ rowsum,
                       const float* __restrict__ colsum,
                       float* __restrict__ dinv) {
    int i = blockIdx.x * 256 + threadIdx.x;
    if (i < NN) {
        float d = 0.5f * (rowsum[i] + colsum[i]);
        if (d == 0.f) d = 1.f;
        dinv[i] = 1.f / sqrtf(d);
    }
}

// Mpack[i][j] = bf16(-cos(th)*A_norm), Mpack[i][2048+j] = bf16(sin(th)*A_norm)
// 32x32 tile; mirror A[j][i] staged through LDS so both global reads are coalesced.
__global__ __launch_bounds__(1024) void build_Mpack_k(
    const float* __restrict__ A, const float* __restrict__ dinv,
    const void* __restrict__ qp, bf16* __restrict__ Mpack,
    const int* __restrict__ flag) {
    __shared__ float tmir[32][33];
    int tx = threadIdx.x, ty = threadIdx.y;
    int j0 = blockIdx.x * 32, i0 = blockIdx.y * 32;
    tmir[ty][tx] = A[(size_t)(j0 + ty) * NN + i0 + tx];   // coalesced mirror tile
    __syncthreads();
    int i = i0 + ty, j = j0 + tx;
    float qv = flag[0] ? __bfloat162float(((const bf16*)qp)[0]) : ((const float*)qp)[0];
    float a = A[(size_t)i * NN + j];     // coalesced
    float b = tmir[tx][ty];              // A[j][i]
    float an = dinv[i] * (0.5f * (a + b)) * dinv[j];
    float th = TWO_PI_F * qv * (a - b);
    float sn, cs;
    sincosf(th, &sn, &cs);
    Mpack[(size_t)i * (2 * NN) + j]      = __float2bfloat16(-cs * an);
    Mpack[(size_t)i * (2 * NN) + NN + j] = __float2bfloat16(sn * an);
}

// Fused: read X tile once -> Xc [2048][1024], Af seg0, BT(X-pack) [1024][4096]
__global__ __launch_bounds__(1024) void convert_X_BT_k(
    const void* __restrict__ xr, const void* __restrict__ xi,
    bf16* __restrict__ Xc, bf16* __restrict__ Af, bf16* __restrict__ BT,
    const int* __restrict__ flag) {
    __shared__ float tr[32][33];
    __shared__ float ti[32][33];
    int tx = threadIdx.x, ty = threadIdx.y;
    int c0 = blockIdx.x * 32, r0 = blockIdx.y * 32;   // grid (16, 64)
    size_t sidx = (size_t)(r0 + ty) * CC + c0 + tx;
    float fr, fi;
    if (flag[0]) {
        fr = __bfloat162float(((const bf16*)xr)[sidx]);
        fi = __bfloat162float(((const bf16*)xi)[sidx]);
    } else {
        fr = ((const float*)xr)[sidx];
        fi = ((const float*)xi)[sidx];
    }
    int r = r0 + ty, c = c0 + tx;
    Xc[(size_t)r * 1024 + c]        = __float2bfloat16(fr);
    Xc[(size_t)r * 1024 + 512 + c]  = __float2bfloat16(fi);
    Af[(size_t)r * 1536 + c]        = __float2bfloat16(-fi);
    Af[(size_t)(NN + r) * 1536 + c] = __float2bfloat16(fr);
    tr[ty][tx] = fr;
    ti[ty][tx] = fi;
    __syncthreads();
    float xrt = tr[tx][ty];   // Xr[r0+tx][c0+ty]
    float xit = ti[tx][ty];
    int n = c0 + ty, k = r0 + tx;
    BT[(size_t)n * 4096 + k]               = __float2bfloat16(xrt);
    BT[(size_t)(512 + n) * 4096 + k]       = __float2bfloat16(xit);
    BT[(size_t)n * 4096 + 2048 + k]        = __float2bfloat16(-xit);
    BT[(size_t)(512 + n) * 4096 + 2048 + k] = __float2bfloat16(xrt);
}

// W transpose: WT bf16 [512][1536] from Wt [1536][512]
__global__ __launch_bounds__(1024) void pack_WT_k(const void* __restrict__ Wt,
                                                  bf16* __restrict__ WT,
                                                  const int* __restrict__ flag) {
    __shared__ float lds[32][33];
    int tx = threadIdx.x, ty = threadIdx.y;
    int k0 = blockIdx.x * 32, o0 = blockIdx.y * 32;
    size_t sidx = (size_t)(k0 + ty) * CC + o0 + tx;
    lds[ty][tx] = flag[0] ? __bfloat162float(((const bf16*)Wt)[sidx])
                          : ((const float*)Wt)[sidx];
    __syncthreads();
    WT[(size_t)(o0 + ty) * 1536 + k0 + tx] = __float2bfloat16(lds[tx][ty]);
}

// BT for G2 from PT fp32 [1024][2048] (Z1^T): fully coalesced sign-copy
__global__ void copy_BT2_k(const float* __restrict__ PT, bf16* __restrict__ BT) {
    int idx = blockIdx.x * 256 + threadIdx.x;
    if (idx >= 1024 * 2048) return;
    int n = idx >> 11, k = idx & 2047;
    float v1 = PT[idx];
    float v2 = (n < 512) ? -PT[(size_t)(n + 512) * 2048 + k]
                         :  PT[(size_t)(n - 512) * 2048 + k];
    BT[(size_t)n * 4096 + k]        = __float2bfloat16(v1);
    BT[(size_t)n * 4096 + 2048 + k] = __float2bfloat16(v2);
}

// Af seg1 from PT: Af[r][512+c] = -PT[512+c][r]; Af[2048+r][512+c] = PT[c][r]
__global__ __launch_bounds__(1024) void pack_Aseg1T_k(const float* __restrict__ PT,
                                                      bf16* __restrict__ Af) {
    __shared__ float t1[32][33];
    __shared__ float t2[32][33];
    int tx = threadIdx.x, ty = threadIdx.y;
    int r0 = blockIdx.x * 32, c0 = blockIdx.y * 32;   // grid (64, 16)
    t1[ty][tx] = PT[(size_t)(c0 + ty) * 2048 + r0 + tx];
    t2[ty][tx] = PT[(size_t)(512 + c0 + ty) * 2048 + r0 + tx];
    __syncthreads();
    int r = r0 + ty, c = c0 + tx;
    Af[(size_t)r * 1536 + 512 + c]        = __float2bfloat16(-t2[tx][ty]);
    Af[(size_t)(NN + r) * 1536 + 512 + c] = __float2bfloat16(t1[tx][ty]);
}

// Af seg2 = 2*P - Xc (signs per complex pack); P normal layout [2048][1024]
__global__ void epi2_k(const float* __restrict__ P, const bf16* __restrict__ Xc,
                       bf16* __restrict__ Af) {
    int idx = blockIdx.x * 256 + threadIdx.x;
    if (idx >= NN * 1024) return;
    int r = idx >> 10, c = idx & 1023;
    float v = 2.f * P[idx] - __bfloat162float(Xc[idx]);
    if (c < 512) Af[(size_t)(NN + r) * 1536 + 1024 + c] = __float2bfloat16(v);
    else         Af[(size_t)r * 1536 + 1024 + (c - 512)] = __float2bfloat16(-v);
}

// out = P + bias (dtype per flag)
__global__ void epi3_k(const float* __restrict__ P, const void* __restrict__ bias,
                       void* __restrict__ out, const int* __restrict__ flag) {
    int idx = blockIdx.x * 256 + threadIdx.x;
    if (idx >= 4096 * CC) return;
    int c = idx & (CC - 1);
    float bb = flag[0] ? __bfloat162float(((const bf16*)bias)[c]) : ((const float*)bias)[c];
    float o = P[idx] + bb;
    if (flag[0]) ((bf16*)out)[idx] = __float2bfloat16(o);
    else         ((float*)out)[idx] = o;
}

// ---------------- split-K MFMA GEMM, BK=64, XOR-swizzled LDS ----------------
// C += A(bf16 [M][K]) @ BT(bf16 [N][K])^T over K-slice blockIdx.z.
// 128x128 tile, 4 waves of 64x64 (4x4 frags), 32 MFMA per barrier pair.
// LDS granule (row, g) holds global colgrp g^(row&7) -> conflict-free ds_read_b128.
// Epilogue: coalesced atomicAdd P[grow*N+gcol].
__global__ __launch_bounds__(256) void gemm_sk_k(
    const bf16* __restrict__ Ab, const bf16* __restrict__ BTb,
    int M, int N, int K, int klen,
    float* __restrict__ P)
{
    __shared__ bf16 sA[128 * 64];
    __shared__ bf16 sB[128 * 64];
    int tid = threadIdx.x;
    int w = tid >> 6, lane = tid & 63;
    int row0 = blockIdx.y * 128, col0 = blockIdx.x * 128;
    int kbase = blockIdx.z * klen;
    int wave_m = (w >> 1) * 64, wave_n = (w & 1) * 64;
    int lm = lane & 15, lq = lane >> 4;

    // staging: chunk c = w*4+i covers LDS rows [c*8, c*8+8); lane: srow = lane/8, granule lane%8
    int srow = lane >> 3;
    int sg   = lane & 7;
    int scol = (sg ^ srow) * 8;          // swizzled source column group
    const bf16 *gA[4], *gB[4];
    bf16 *lA[4], *lB[4];
#pragma unroll
    for (int i = 0; i < 4; ++i) {
        int c = w * 4 + i;
        int row = c * 8 + srow;
        gA[i] = Ab  + (size_t)(row0 + row) * K + kbase + scol;
        gB[i] = BTb + (size_t)(col0 + row) * K + kbase + scol;
        lA[i] = sA + c * 512 + lane * 8;   // 512 bf16 = 1 KB per chunk
        lB[i] = sB + c * 512 + lane * 8;
    }

    floatx4 acc[4][4];
#pragma unroll
    for (int mf = 0; mf < 4; ++mf)
#pragma unroll
        for (int nf = 0; nf < 4; ++nf)
            acc[mf][nf] = (floatx4){0.f, 0.f, 0.f, 0.f};

    for (int kk = 0; kk < klen; kk += 64) {
        __syncthreads();
#pragma unroll
        for (int i = 0; i < 4; ++i) {
            gld16(gA[i] + kk, lA[i]);
            gld16(gB[i] + kk, lB[i]);
        }
        __syncthreads();
#pragma unroll
        for (int ks = 0; ks < 2; ++ks) {
            short8 af[4], bfv[4];
#pragma unroll
            for (int mf = 0; mf < 4; ++mf) {
                int row = wave_m + mf * 16 + lm;
                int g = (ks * 4 + lq) ^ (row & 7);
                af[mf] = *(const short8*)&sA[row * 64 + g * 8];
            }
#pragma unroll
            for (int nf = 0; nf < 4; ++nf) {
                int row = wave_n + nf * 16 + lm;
                int g = (ks * 4 + lq) ^ (row & 7);
                bfv[nf] = *(const short8*)&sB[row * 64 + g * 8];
            }
#pragma unroll
            for (int mf = 0; mf < 4; ++mf)
#pragma unroll
                for (int nf = 0; nf < 4; ++nf)
                    acc[mf][nf] = __builtin_amdgcn_mfma_f32_16x16x32_bf16(
                        af[mf], bfv[nf], acc[mf][nf], 0, 0, 0);
        }
    }

#pragma unroll
    for (int mf = 0; mf < 4; ++mf) {
#pragma unroll
        for (int nf = 0; nf < 4; ++nf) {
            int gcol = col0 + wave_n + nf * 16 + lm;
#pragma unroll
            for (int r = 0; r < 4; ++r) {
                int grow = row0 + wave_m + mf * 16 + lq * 4 + r;
                atomicAdd(&P[(size_t)grow * N + gcol], acc[mf][nf][r]);
            }
        }
    }
}

// ---------------- launcher ----------------

extern "C" void kernel_launch(void* const* d_in, const int* in_sizes, int n_in,
                              void* d_out, int out_size, void* d_ws, size_t ws_size,
                              hipStream_t stream) {
    const void* Xr_in = d_in[0];
    const void* Xi_in = d_in[1];
    const void* edges = d_in[2];
    const void* q     = d_in[3];
    const void* ew    = d_in[4];
    const void* Wt    = d_in[5];
    const void* bias  = d_in[6];

    char* base = (char*)d_ws;
    const size_t MB = 1024 * 1024;
    float* A      = (float*)(base);                 // 16 MB during prep
    float* colsum = (float*)(base + 16 * MB);       // 8 KB, adjacent to A (shared memset)
    bf16*  Xc     = (bf16*)(base);                  // 4 MB (after A dead)
    float* P      = (float*)(base + 4 * MB);        // 8 MB fp32 accumulator (PT for G1)
    bf16*  Mpack  = (bf16*)(base + 17 * MB);        // 16 MB
    bf16*  Af     = (bf16*)(base + 33 * MB);        // 12 MB
    bf16*  BTb    = (bf16*)(base + 45 * MB);        // 8 MB
    bf16*  WT     = (bf16*)(base + 53 * MB);        // 1.5 MB
    float* rowsum = (float*)(base + 55 * MB);
    float* dinv   = (float*)(base + 55 * MB + 16 * 1024);
    int*   flag   = (int*)  (base + 55 * MB + 32 * 1024);

    detect_k<<<1, 64, 0, stream>>>((const unsigned int*)q, (const unsigned int*)edges, flag);

    hipMemsetAsync(A, 0, 16 * MB + 8 * 1024, stream);   // A + colsum in one pass

    scatter_edges_k<<<NEDGE / 256, 256, 0, stream>>>(edges, ew, A, flag);
    row_sums_k<<<NN, 256, 0, stream>>>(A, rowsum);
    col_sums_k<<<dim3(NN / 256, NN / 64), 256, 0, stream>>>(A, colsum);
    dinv_k<<<NN / 256, 256, 0, stream>>>(rowsum, colsum, dinv);
    build_Mpack_k<<<dim3(NN / 32, NN / 32), dim3(32, 32), 0, stream>>>(A, dinv, q, Mpack, flag);

    // A dead -> Xc/P may reuse base
    convert_X_BT_k<<<dim3(CC / 32, NN / 32), dim3(32, 32), 0, stream>>>(
        Xr_in, Xi_in, Xc, Af, BTb, flag);
    pack_WT_k<<<dim3(1536 / 32, CC / 32), dim3(32, 32), 0, stream>>>(Wt, WT, flag);

    // G1 (operand-swapped): PT[1024][2048] = XpackT @ Mpack^T  (splitK=8)
    hipMemsetAsync(P, 0, 8 * MB, stream);
    gemm_sk_k<<<dim3(NN / 128, 1024 / 128, 8), 256, 0, stream>>>(
        BTb, Mpack, 1024, NN, 4096, 512, P);
    copy_BT2_k<<<(1024 * 2048) / 256, 256, 0, stream>>>(P, BTb);
    pack_Aseg1T_k<<<dim3(2048 / 32, 512 / 32), dim3(32, 32), 0, stream>>>(P, Af);

    // G2: P = Mpack @ Z1packT^T (splitK=8) ; Af seg2 = 2P - Xc
    hipMemsetAsync(P, 0, 8 * MB, stream);
    gemm_sk_k<<<dim3(1024 / 128, NN / 128, 8), 256, 0, stream>>>(
        Mpack, BTb, NN, 1024, 4096, 512, P);
    epi2_k<<<(NN * 1024) / 256, 256, 0, stream>>>(P, Xc, Af);

    // G3: P = Af @ WT^T (M=4096, N=512, K=1536, splitK=8) ; out = P + bias
    hipMemsetAsync(P, 0, 8 * MB, stream);
    gemm_sk_k<<<dim3(CC / 128, 4096 / 128, 8), 256, 0, stream>>>(
        Af, WT, 4096, CC, 1536, 192, P);
    epi3_k<<<(4096 * CC) / 256, 256, 0, stream>>>(P, bias, d_out, flag);
}

// Round 11
// 240.696 us; speedup vs baseline: 1.4508x; 1.4508x over previous
//
#include <hip/hip_runtime.h>
#include <hip/hip_bf16.h>
#include <math.h>

#define NN 2048
#define CC 512
#define NEDGE 65536

typedef __hip_bfloat16 bf16;
typedef __attribute__((ext_vector_type(8))) short short8;
typedef __attribute__((ext_vector_type(4))) float floatx4;

static constexpr float TWO_PI_F = 6.2831853071795864769f;

// async global->LDS direct copy, 16 B per lane (dest = wave-uniform base + lane*16)
__device__ __forceinline__ void gld16(const void* g, void* l) {
    __builtin_amdgcn_global_load_lds(
        (const __attribute__((address_space(1))) unsigned int*)(unsigned long long)(uintptr_t)g,
        (__attribute__((address_space(3))) unsigned int*)(unsigned long long)(uintptr_t)l,
        16, 0, 0);
}

// ---------------- detector + deg zero ----------------
// flag[0]: bf16 float mode. flag[1]: int64 edges. Also zeroes deg[2048].
__global__ __launch_bounds__(256) void detect_k(const unsigned int* __restrict__ qword,
                                                const unsigned int* __restrict__ ewords,
                                                int* __restrict__ flag,
                                                float* __restrict__ deg) {
    int tid = threadIdx.x;
#pragma unroll
    for (int i = 0; i < 8; ++i) deg[tid * 8 + i] = 0.f;
    if (tid < 64) {
        unsigned int w0 = ewords[2 * tid + 1];
        unsigned int w1 = ewords[128 + 2 * tid + 1];
        unsigned long long b = __ballot((w0 | w1) != 0u);
        if (tid == 0) {
            flag[0] = ((qword[0] & 0xFFFFu) == 0x3E80u) ? 1 : 0;
            flag[1] = (b == 0ull) ? 1 : 0;
        }
    }
}

// ---------------- prep kernels ----------------

__global__ void scatter_edges_k(const void* __restrict__ edges,
                                const void* __restrict__ w,
                                float* __restrict__ A,
                                const int* __restrict__ flag) {
    int e = blockIdx.x * 256 + threadIdx.x;
    if (e >= NEDGE) return;
    int f, t;
    if (flag[1]) {
        f = (int)((const long long*)edges)[e];
        t = (int)((const long long*)edges)[NEDGE + e];
    } else {
        f = ((const int*)edges)[e];
        t = ((const int*)edges)[NEDGE + e];
    }
    float wv = flag[0] ? __bfloat162float(((const bf16*)w)[e]) : ((const float*)w)[e];
    f &= (NN - 1); t &= (NN - 1);
    atomicAdd(&A[(size_t)f * NN + t], wv);
}

// deg[x] = rowsum(A)[x] + colsum(A)[x], sparse (A is ~1.5% nonzero)
__global__ void deg_k(const float* __restrict__ A, float* __restrict__ deg) {
    int idx = blockIdx.x * 256 + threadIdx.x;
    float v = A[idx];
    if (v != 0.f) {
        int r = idx >> 11, c = idx & (NN - 1);
        atomicAdd(&deg[r], v);
        atomicAdd(&deg[c], v);
    }
}

// Mpack[i][j] = bf16(-cos(th)*A_norm), Mpack[i][2048+j] = bf16(sin(th)*A_norm)
// dinv computed inline from deg; mirror A[j][i] staged via LDS (coalesced).
__global__ __launch_bounds__(1024) void build_Mpack_k(
    const float* __restrict__ A, const float* __restrict__ deg,
    const void* __restrict__ qp, bf16* __restrict__ Mpack,
    const int* __restrict__ flag) {
    __shared__ float tmir[32][33];
    int tx = threadIdx.x, ty = threadIdx.y;
    int j0 = blockIdx.x * 32, i0 = blockIdx.y * 32;
    tmir[ty][tx] = A[(size_t)(j0 + ty) * NN + i0 + tx];
    __syncthreads();
    int i = i0 + ty, j = j0 + tx;
    float qv = flag[0] ? __bfloat162float(((const bf16*)qp)[0]) : ((const float*)qp)[0];
    float di = 0.5f * deg[i]; di = (di == 0.f) ? 1.f : di;
    float dj = 0.5f * deg[j]; dj = (dj == 0.f) ? 1.f : dj;
    float a = A[(size_t)i * NN + j];
    float b = tmir[tx][ty];              // A[j][i]
    float an = rsqrtf(di) * (0.5f * (a + b)) * rsqrtf(dj);
    float th = TWO_PI_F * qv * (a - b);
    float sn, cs;
    sincosf(th, &sn, &cs);
    Mpack[(size_t)i * (2 * NN) + j]      = __float2bfloat16(-cs * an);
    Mpack[(size_t)i * (2 * NN) + NN + j] = __float2bfloat16(sn * an);
}

// Read X tile once -> Af seg0 + BT(X-pack) [1024][4096]
__global__ __launch_bounds__(1024) void convert_X_BT_k(
    const void* __restrict__ xr, const void* __restrict__ xi,
    bf16* __restrict__ Af, bf16* __restrict__ BT,
    const int* __restrict__ flag) {
    __shared__ float tr[32][33];
    __shared__ float ti[32][33];
    int tx = threadIdx.x, ty = threadIdx.y;
    int c0 = blockIdx.x * 32, r0 = blockIdx.y * 32;   // grid (16, 64)
    size_t sidx = (size_t)(r0 + ty) * CC + c0 + tx;
    float fr, fi;
    if (flag[0]) {
        fr = __bfloat162float(((const bf16*)xr)[sidx]);
        fi = __bfloat162float(((const bf16*)xi)[sidx]);
    } else {
        fr = ((const float*)xr)[sidx];
        fi = ((const float*)xi)[sidx];
    }
    int r = r0 + ty, c = c0 + tx;
    Af[(size_t)r * 1536 + c]        = __float2bfloat16(-fi);
    Af[(size_t)(NN + r) * 1536 + c] = __float2bfloat16(fr);
    tr[ty][tx] = fr;
    ti[ty][tx] = fi;
    __syncthreads();
    float xrt = tr[tx][ty];   // Xr[r0+tx][c0+ty]
    float xit = ti[tx][ty];
    int n = c0 + ty, k = r0 + tx;
    BT[(size_t)n * 4096 + k]                = __float2bfloat16(xrt);
    BT[(size_t)(512 + n) * 4096 + k]        = __float2bfloat16(xit);
    BT[(size_t)n * 4096 + 2048 + k]         = __float2bfloat16(-xit);
    BT[(size_t)(512 + n) * 4096 + 2048 + k] = __float2bfloat16(xrt);
}

// W transpose: WT bf16 [512][1536] from Wt [1536][512]
__global__ __launch_bounds__(1024) void pack_WT_k(const void* __restrict__ Wt,
                                                  bf16* __restrict__ WT,
                                                  const int* __restrict__ flag) {
    __shared__ float lds[32][33];
    int tx = threadIdx.x, ty = threadIdx.y;
    int k0 = blockIdx.x * 32, o0 = blockIdx.y * 32;
    size_t sidx = (size_t)(k0 + ty) * CC + o0 + tx;
    lds[ty][tx] = flag[0] ? __bfloat162float(((const bf16*)Wt)[sidx])
                          : ((const float*)Wt)[sidx];
    __syncthreads();
    WT[(size_t)(o0 + ty) * 1536 + k0 + tx] = __float2bfloat16(lds[tx][ty]);
}

// Fused PT consumer: sum 4 bf16 partials of PT [1024][2048], emit BT (G2 B-operand)
// and Af seg1. Grid (2048/32, 512/32), block (32,32).
__global__ __launch_bounds__(1024) void packPT_k(const bf16* __restrict__ Pb,
                                                 bf16* __restrict__ BT,
                                                 bf16* __restrict__ Af) {
    __shared__ float t1[32][33];
    __shared__ float t2[32][33];
    int tx = threadIdx.x, ty = threadIdx.y;
    int k0 = blockIdx.x * 32, n0 = blockIdx.y * 32;   // n0 in [0,512)
    size_t i1 = (size_t)(n0 + ty) * 2048 + k0 + tx;
    size_t i2 = (size_t)(512 + n0 + ty) * 2048 + k0 + tx;
    float s1 = 0.f, s2 = 0.f;
#pragma unroll
    for (int z = 0; z < 4; ++z) {
        s1 += __bfloat162float(Pb[(size_t)z * 1024 * 2048 + i1]);
        s2 += __bfloat162float(Pb[(size_t)z * 1024 * 2048 + i2]);
    }
    t1[ty][tx] = s1;
    t2[ty][tx] = s2;
    BT[(size_t)(n0 + ty) * 4096 + k0 + tx]              = __float2bfloat16(s1);
    BT[(size_t)(n0 + ty) * 4096 + 2048 + k0 + tx]       = __float2bfloat16(-s2);
    BT[(size_t)(512 + n0 + ty) * 4096 + k0 + tx]        = __float2bfloat16(s2);
    BT[(size_t)(512 + n0 + ty) * 4096 + 2048 + k0 + tx] = __float2bfloat16(s1);
    __syncthreads();
    // Af[r][512+c] = -PT[512+c][r]; Af[2048+r][512+c] = PT[c][r]  (r=k0+ty, c=n0+tx)
    Af[(size_t)(k0 + ty) * 1536 + 512 + n0 + tx]        = __float2bfloat16(-t2[tx][ty]);
    Af[(size_t)(NN + k0 + ty) * 1536 + 512 + n0 + tx]   = __float2bfloat16(t1[tx][ty]);
}

// Af seg2 = 2*sum(P partials) - X (reads X inputs directly, dtype per flag)
__global__ void epi2_k(const bf16* __restrict__ Pb,
                       const void* __restrict__ xr, const void* __restrict__ xi,
                       bf16* __restrict__ Af, const int* __restrict__ flag) {
    int idx = blockIdx.x * 256 + threadIdx.x;
    if (idx >= NN * 1024) return;
    int r = idx >> 10, c = idx & 1023;
    float s = 0.f;
#pragma unroll
    for (int z = 0; z < 4; ++z)
        s += __bfloat162float(Pb[(size_t)z * NN * 1024 + idx]);
    size_t xoff = (size_t)r * CC + (c & (CC - 1));
    float xv;
    if (c < 512) xv = flag[0] ? __bfloat162float(((const bf16*)xr)[xoff]) : ((const float*)xr)[xoff];
    else         xv = flag[0] ? __bfloat162float(((const bf16*)xi)[xoff]) : ((const float*)xi)[xoff];
    float v = 2.f * s - xv;
    if (c < 512) Af[(size_t)(NN + r) * 1536 + 1024 + c] = __float2bfloat16(v);
    else         Af[(size_t)r * 1536 + 1024 + (c - 512)] = __float2bfloat16(-v);
}

// out = sum(P partials) + bias (dtype per flag)
__global__ void epi3_k(const bf16* __restrict__ Pb, const void* __restrict__ bias,
                       void* __restrict__ out, const int* __restrict__ flag) {
    int idx = blockIdx.x * 256 + threadIdx.x;
    if (idx >= 4096 * CC) return;
    int c = idx & (CC - 1);
    float s = 0.f;
#pragma unroll
    for (int z = 0; z < 4; ++z)
        s += __bfloat162float(Pb[(size_t)z * 4096 * CC + idx]);
    float bb = flag[0] ? __bfloat162float(((const bf16*)bias)[c]) : ((const float*)bias)[c];
    float o = s + bb;
    if (flag[0]) ((bf16*)out)[idx] = __float2bfloat16(o);
    else         ((float*)out)[idx] = o;
}

// ---------------- split-K MFMA GEMM, BK=64, XOR-swizzled LDS ----------------
// Slice z writes its own bf16 partial: Pb[z*M*N + grow*N + gcol] (plain stores,
// no memset, no atomic RMW). 128x128 tile, 4 waves of 64x64, 32 MFMA/barrier-pair.
__global__ __launch_bounds__(256) void gemm_sk_k(
    const bf16* __restrict__ Ab, const bf16* __restrict__ BTb,
    int M, int N, int K, int klen,
    bf16* __restrict__ Pb)
{
    __shared__ bf16 sA[128 * 64];
    __shared__ bf16 sB[128 * 64];
    int tid = threadIdx.x;
    int w = tid >> 6, lane = tid & 63;
    int row0 = blockIdx.y * 128, col0 = blockIdx.x * 128;
    int kbase = blockIdx.z * klen;
    int wave_m = (w >> 1) * 64, wave_n = (w & 1) * 64;
    int lm = lane & 15, lq = lane >> 4;

    int srow = lane >> 3;
    int sg   = lane & 7;
    int scol = (sg ^ srow) * 8;          // swizzled source column group
    const bf16 *gA[4], *gB[4];
    bf16 *lA[4], *lB[4];
#pragma unroll
    for (int i = 0; i < 4; ++i) {
        int c = w * 4 + i;
        int row = c * 8 + srow;
        gA[i] = Ab  + (size_t)(row0 + row) * K + kbase + scol;
        gB[i] = BTb + (size_t)(col0 + row) * K + kbase + scol;
        lA[i] = sA + c * 512 + lane * 8;
        lB[i] = sB + c * 512 + lane * 8;
    }

    floatx4 acc[4][4];
#pragma unroll
    for (int mf = 0; mf < 4; ++mf)
#pragma unroll
        for (int nf = 0; nf < 4; ++nf)
            acc[mf][nf] = (floatx4){0.f, 0.f, 0.f, 0.f};

    for (int kk = 0; kk < klen; kk += 64) {
        __syncthreads();
#pragma unroll
        for (int i = 0; i < 4; ++i) {
            gld16(gA[i] + kk, lA[i]);
            gld16(gB[i] + kk, lB[i]);
        }
        __syncthreads();
#pragma unroll
        for (int ks = 0; ks < 2; ++ks) {
            short8 af[4], bfv[4];
#pragma unroll
            for (int mf = 0; mf < 4; ++mf) {
                int row = wave_m + mf * 16 + lm;
                int g = (ks * 4 + lq) ^ (row & 7);
                af[mf] = *(const short8*)&sA[row * 64 + g * 8];
            }
#pragma unroll
            for (int nf = 0; nf < 4; ++nf) {
                int row = wave_n + nf * 16 + lm;
                int g = (ks * 4 + lq) ^ (row & 7);
                bfv[nf] = *(const short8*)&sB[row * 64 + g * 8];
            }
#pragma unroll
            for (int mf = 0; mf < 4; ++mf)
#pragma unroll
                for (int nf = 0; nf < 4; ++nf)
                    acc[mf][nf] = __builtin_amdgcn_mfma_f32_16x16x32_bf16(
                        af[mf], bfv[nf], acc[mf][nf], 0, 0, 0);
        }
    }

    bf16* slice = Pb + (size_t)blockIdx.z * M * N;
#pragma unroll
    for (int mf = 0; mf < 4; ++mf) {
#pragma unroll
        for (int nf = 0; nf < 4; ++nf) {
            int gcol = col0 + wave_n + nf * 16 + lm;
#pragma unroll
            for (int r = 0; r < 4; ++r) {
                int grow = row0 + wave_m + mf * 16 + lq * 4 + r;
                slice[(size_t)grow * N + gcol] = __float2bfloat16(acc[mf][nf][r]);
            }
        }
    }
}

// ---------------- launcher ----------------

extern "C" void kernel_launch(void* const* d_in, const int* in_sizes, int n_in,
                              void* d_out, int out_size, void* d_ws, size_t ws_size,
                              hipStream_t stream) {
    const void* Xr_in = d_in[0];
    const void* Xi_in = d_in[1];
    const void* edges = d_in[2];
    const void* q     = d_in[3];
    const void* ew    = d_in[4];
    const void* Wt    = d_in[5];
    const void* bias  = d_in[6];

    char* base = (char*)d_ws;
    const size_t MB = 1024 * 1024;
    float* A      = (float*)(base);                 // 16 MB during prep (dead after build_Mpack)
    bf16*  Pb     = (bf16*)(base);                  // 16 MB: 4 bf16 partial slices (reused 3x)
    bf16*  Mpack  = (bf16*)(base + 16 * MB);        // 16 MB
    bf16*  Af     = (bf16*)(base + 32 * MB);        // 12 MB
    bf16*  BTb    = (bf16*)(base + 44 * MB);        // 8 MB
    bf16*  WT     = (bf16*)(base + 52 * MB);        // 1.5 MB
    float* deg    = (float*)(base + 53 * MB + 512 * 1024);  // 8 KB
    int*   flag   = (int*)  (base + 53 * MB + 520 * 1024);  // 8 B

    detect_k<<<1, 256, 0, stream>>>((const unsigned int*)q, (const unsigned int*)edges,
                                    flag, deg);
    hipMemsetAsync(A, 0, 16 * MB, stream);

    scatter_edges_k<<<NEDGE / 256, 256, 0, stream>>>(edges, ew, A, flag);
    deg_k<<<(NN * NN) / 256, 256, 0, stream>>>(A, deg);
    build_Mpack_k<<<dim3(NN / 32, NN / 32), dim3(32, 32), 0, stream>>>(A, deg, q, Mpack, flag);

    // A dead -> Pb may reuse base
    convert_X_BT_k<<<dim3(CC / 32, NN / 32), dim3(32, 32), 0, stream>>>(
        Xr_in, Xi_in, Af, BTb, flag);
    pack_WT_k<<<dim3(1536 / 32, CC / 32), dim3(32, 32), 0, stream>>>(Wt, WT, flag);

    // G1 (operand-swapped): PT[1024][2048] = XpackT @ Mpack^T, splitK=4 bf16 partials
    gemm_sk_k<<<dim3(NN / 128, 1024 / 128, 4), 256, 0, stream>>>(
        BTb, Mpack, 1024, NN, 4096, 1024, Pb);
    packPT_k<<<dim3(2048 / 32, 512 / 32), dim3(32, 32), 0, stream>>>(Pb, BTb, Af);

    // G2: P = Mpack @ Z1packT^T, splitK=4 ; Af seg2 = 2*sum(P) - X
    gemm_sk_k<<<dim3(1024 / 128, NN / 128, 4), 256, 0, stream>>>(
        Mpack, BTb, NN, 1024, 4096, 1024, Pb);
    epi2_k<<<(NN * 1024) / 256, 256, 0, stream>>>(Pb, Xr_in, Xi_in, Af, flag);

    // G3: P = Af @ WT^T (M=4096, N=512, K=1536, splitK=4) ; out = sum(P) + bias
    gemm_sk_k<<<dim3(CC / 128, 4096 / 128, 4), 256, 0, stream>>>(
        Af, WT, 4096, CC, 1536, 384, Pb);
    epi3_k<<<(4096 * CC) / 256, 256, 0, stream>>>(Pb, bias, d_out, flag);
}

// Round 12
// 204.205 us; speedup vs baseline: 1.7101x; 1.1787x over previous
//
#include <hip/hip_runtime.h>
#include <hip/hip_bf16.h>
#include <math.h>

#define NN 2048
#define CC 512
#define NEDGE 65536

typedef __hip_bfloat16 bf16;
typedef __attribute__((ext_vector_type(8))) short short8;
typedef __attribute__((ext_vector_type(4))) float floatx4;

static constexpr float TWO_PI_F = 6.2831853071795864769f;

// async global->LDS direct copy, 16 B per lane (dest = wave-uniform base + lane*16)
__device__ __forceinline__ void gld16(const void* g, void* l) {
    __builtin_amdgcn_global_load_lds(
        (const __attribute__((address_space(1))) unsigned int*)(unsigned long long)(uintptr_t)g,
        (__attribute__((address_space(3))) unsigned int*)(unsigned long long)(uintptr_t)l,
        16, 0, 0);
}

// ---------------- detector + colsum zero ----------------
// flag[0]: bf16 float mode. flag[1]: int64 edges. Also zeroes colsum[2048].
__global__ __launch_bounds__(256) void detect_k(const unsigned int* __restrict__ qword,
                                                const unsigned int* __restrict__ ewords,
                                                int* __restrict__ flag,
                                                float* __restrict__ colsum) {
    int tid = threadIdx.x;
#pragma unroll
    for (int i = 0; i < 8; ++i) colsum[tid * 8 + i] = 0.f;
    if (tid < 64) {
        unsigned int w0 = ewords[2 * tid + 1];
        unsigned int w1 = ewords[128 + 2 * tid + 1];
        unsigned long long b = __ballot((w0 | w1) != 0u);
        if (tid == 0) {
            flag[0] = ((qword[0] & 0xFFFFu) == 0x3E80u) ? 1 : 0;
            flag[1] = (b == 0ull) ? 1 : 0;
        }
    }
}

// ---------------- prep kernels ----------------

__global__ void scatter_edges_k(const void* __restrict__ edges,
                                const void* __restrict__ w,
                                float* __restrict__ A,
                                const int* __restrict__ flag) {
    int e = blockIdx.x * 256 + threadIdx.x;
    if (e >= NEDGE) return;
    int f, t;
    if (flag[1]) {
        f = (int)((const long long*)edges)[e];
        t = (int)((const long long*)edges)[NEDGE + e];
    } else {
        f = ((const int*)edges)[e];
        t = ((const int*)edges)[NEDGE + e];
    }
    float wv = flag[0] ? __bfloat162float(((const bf16*)w)[e]) : ((const float*)w)[e];
    f &= (NN - 1); t &= (NN - 1);
    atomicAdd(&A[(size_t)f * NN + t], wv);
}

// rowsum[i] = sum_j A[i][j]  (atomic-free, coalesced)
__global__ void row_sums_k(const float* __restrict__ A, float* __restrict__ rowsum) {
    int i = blockIdx.x;
    float s = 0.f;
    for (int j = threadIdx.x; j < NN; j += 256) s += A[(size_t)i * NN + j];
    __shared__ float red[256];
    red[threadIdx.x] = s;
    __syncthreads();
    for (int off = 128; off > 0; off >>= 1) {
        if (threadIdx.x < off) red[threadIdx.x] += red[threadIdx.x + off];
        __syncthreads();
    }
    if (threadIdx.x == 0) rowsum[i] = red[0];
}

// colsum[j] += partial over 64-row stripe (8192 atomics total, 4 per address)
__global__ void col_sums_k(const float* __restrict__ A, float* __restrict__ colsum) {
    int col = blockIdx.x * 256 + threadIdx.x;
    int r0 = blockIdx.y * 64;
    float s = 0.f;
    for (int r = r0; r < r0 + 64; ++r) s += A[(size_t)r * NN + col];
    atomicAdd(&colsum[col], s);
}

// Mpack[i][j] = bf16(-cos(th)*A_norm), Mpack[i][2048+j] = bf16(sin(th)*A_norm)
// deg = rowsum+colsum, dinv inline; mirror A[j][i] staged via LDS (coalesced).
__global__ __launch_bounds__(1024) void build_Mpack_k(
    const float* __restrict__ A,
    const float* __restrict__ rowsum, const float* __restrict__ colsum,
    const void* __restrict__ qp, bf16* __restrict__ Mpack,
    const int* __restrict__ flag) {
    __shared__ float tmir[32][33];
    int tx = threadIdx.x, ty = threadIdx.y;
    int j0 = blockIdx.x * 32, i0 = blockIdx.y * 32;
    tmir[ty][tx] = A[(size_t)(j0 + ty) * NN + i0 + tx];
    __syncthreads();
    int i = i0 + ty, j = j0 + tx;
    float qv = flag[0] ? __bfloat162float(((const bf16*)qp)[0]) : ((const float*)qp)[0];
    float di = 0.5f * (rowsum[i] + colsum[i]); di = (di == 0.f) ? 1.f : di;
    float dj = 0.5f * (rowsum[j] + colsum[j]); dj = (dj == 0.f) ? 1.f : dj;
    float a = A[(size_t)i * NN + j];
    float b = tmir[tx][ty];              // A[j][i]
    float an = rsqrtf(di) * (0.5f * (a + b)) * rsqrtf(dj);
    float th = TWO_PI_F * qv * (a - b);
    float sn, cs;
    sincosf(th, &sn, &cs);
    Mpack[(size_t)i * (2 * NN) + j]      = __float2bfloat16(-cs * an);
    Mpack[(size_t)i * (2 * NN) + NN + j] = __float2bfloat16(sn * an);
}

// Read X tile once -> Af seg0 + BT(X-pack) [1024][4096]
__global__ __launch_bounds__(1024) void convert_X_BT_k(
    const void* __restrict__ xr, const void* __restrict__ xi,
    bf16* __restrict__ Af, bf16* __restrict__ BT,
    const int* __restrict__ flag) {
    __shared__ float tr[32][33];
    __shared__ float ti[32][33];
    int tx = threadIdx.x, ty = threadIdx.y;
    int c0 = blockIdx.x * 32, r0 = blockIdx.y * 32;   // grid (16, 64)
    size_t sidx = (size_t)(r0 + ty) * CC + c0 + tx;
    float fr, fi;
    if (flag[0]) {
        fr = __bfloat162float(((const bf16*)xr)[sidx]);
        fi = __bfloat162float(((const bf16*)xi)[sidx]);
    } else {
        fr = ((const float*)xr)[sidx];
        fi = ((const float*)xi)[sidx];
    }
    int r = r0 + ty, c = c0 + tx;
    Af[(size_t)r * 1536 + c]        = __float2bfloat16(-fi);
    Af[(size_t)(NN + r) * 1536 + c] = __float2bfloat16(fr);
    tr[ty][tx] = fr;
    ti[ty][tx] = fi;
    __syncthreads();
    float xrt = tr[tx][ty];   // Xr[r0+tx][c0+ty]
    float xit = ti[tx][ty];
    int n = c0 + ty, k = r0 + tx;
    BT[(size_t)n * 4096 + k]                = __float2bfloat16(xrt);
    BT[(size_t)(512 + n) * 4096 + k]        = __float2bfloat16(xit);
    BT[(size_t)n * 4096 + 2048 + k]         = __float2bfloat16(-xit);
    BT[(size_t)(512 + n) * 4096 + 2048 + k] = __float2bfloat16(xrt);
}

// W transpose: WT bf16 [512][1536] from Wt [1536][512]
__global__ __launch_bounds__(1024) void pack_WT_k(const void* __restrict__ Wt,
                                                  bf16* __restrict__ WT,
                                                  const int* __restrict__ flag) {
    __shared__ float lds[32][33];
    int tx = threadIdx.x, ty = threadIdx.y;
    int k0 = blockIdx.x * 32, o0 = blockIdx.y * 32;
    size_t sidx = (size_t)(k0 + ty) * CC + o0 + tx;
    lds[ty][tx] = flag[0] ? __bfloat162float(((const bf16*)Wt)[sidx])
                          : ((const float*)Wt)[sidx];
    __syncthreads();
    WT[(size_t)(o0 + ty) * 1536 + k0 + tx] = __float2bfloat16(lds[tx][ty]);
}

// Fused PT consumer: sum 4 bf16 partials of PT [1024][2048], emit BT (G2 B-operand)
// and Af seg1. Grid (2048/32, 512/32), block (32,32).
__global__ __launch_bounds__(1024) void packPT_k(const bf16* __restrict__ Pb,
                                                 bf16* __restrict__ BT,
                                                 bf16* __restrict__ Af) {
    __shared__ float t1[32][33];
    __shared__ float t2[32][33];
    int tx = threadIdx.x, ty = threadIdx.y;
    int k0 = blockIdx.x * 32, n0 = blockIdx.y * 32;   // n0 in [0,512)
    size_t i1 = (size_t)(n0 + ty) * 2048 + k0 + tx;
    size_t i2 = (size_t)(512 + n0 + ty) * 2048 + k0 + tx;
    float s1 = 0.f, s2 = 0.f;
#pragma unroll
    for (int z = 0; z < 4; ++z) {
        s1 += __bfloat162float(Pb[(size_t)z * 1024 * 2048 + i1]);
        s2 += __bfloat162float(Pb[(size_t)z * 1024 * 2048 + i2]);
    }
    t1[ty][tx] = s1;
    t2[ty][tx] = s2;
    BT[(size_t)(n0 + ty) * 4096 + k0 + tx]              = __float2bfloat16(s1);
    BT[(size_t)(n0 + ty) * 4096 + 2048 + k0 + tx]       = __float2bfloat16(-s2);
    BT[(size_t)(512 + n0 + ty) * 4096 + k0 + tx]        = __float2bfloat16(s2);
    BT[(size_t)(512 + n0 + ty) * 4096 + 2048 + k0 + tx] = __float2bfloat16(s1);
    __syncthreads();
    // Af[r][512+c] = -PT[512+c][r]; Af[2048+r][512+c] = PT[c][r]  (r=k0+ty, c=n0+tx)
    Af[(size_t)(k0 + ty) * 1536 + 512 + n0 + tx]        = __float2bfloat16(-t2[tx][ty]);
    Af[(size_t)(NN + k0 + ty) * 1536 + 512 + n0 + tx]   = __float2bfloat16(t1[tx][ty]);
}

// Af seg2 = 2*sum(P partials) - X (reads X inputs directly, dtype per flag)
__global__ void epi2_k(const bf16* __restrict__ Pb,
                       const void* __restrict__ xr, const void* __restrict__ xi,
                       bf16* __restrict__ Af, const int* __restrict__ flag) {
    int idx = blockIdx.x * 256 + threadIdx.x;
    if (idx >= NN * 1024) return;
    int r = idx >> 10, c = idx & 1023;
    float s = 0.f;
#pragma unroll
    for (int z = 0; z < 4; ++z)
        s += __bfloat162float(Pb[(size_t)z * NN * 1024 + idx]);
    size_t xoff = (size_t)r * CC + (c & (CC - 1));
    float xv;
    if (c < 512) xv = flag[0] ? __bfloat162float(((const bf16*)xr)[xoff]) : ((const float*)xr)[xoff];
    else         xv = flag[0] ? __bfloat162float(((const bf16*)xi)[xoff]) : ((const float*)xi)[xoff];
    float v = 2.f * s - xv;
    if (c < 512) Af[(size_t)(NN + r) * 1536 + 1024 + c] = __float2bfloat16(v);
    else         Af[(size_t)r * 1536 + 1024 + (c - 512)] = __float2bfloat16(-v);
}

// out = sum(P partials) + bias (dtype per flag)
__global__ void epi3_k(const bf16* __restrict__ Pb, const void* __restrict__ bias,
                       void* __restrict__ out, const int* __restrict__ flag) {
    int idx = blockIdx.x * 256 + threadIdx.x;
    if (idx >= 4096 * CC) return;
    int c = idx & (CC - 1);
    float s = 0.f;
#pragma unroll
    for (int z = 0; z < 4; ++z)
        s += __bfloat162float(Pb[(size_t)z * 4096 * CC + idx]);
    float bb = flag[0] ? __bfloat162float(((const bf16*)bias)[c]) : ((const float*)bias)[c];
    float o = s + bb;
    if (flag[0]) ((bf16*)out)[idx] = __float2bfloat16(o);
    else         ((float*)out)[idx] = o;
}

// ---------------- split-K MFMA GEMM, BK=64, XOR-swizzled LDS ----------------
// Slice z writes its own bf16 partial: Pb[z*M*N + grow*N + gcol] (plain stores,
// no memset, no atomic RMW). 128x128 tile, 4 waves of 64x64, 32 MFMA/barrier-pair.
__global__ __launch_bounds__(256) void gemm_sk_k(
    const bf16* __restrict__ Ab, const bf16* __restrict__ BTb,
    int M, int N, int K, int klen,
    bf16* __restrict__ Pb)
{
    __shared__ bf16 sA[128 * 64];
    __shared__ bf16 sB[128 * 64];
    int tid = threadIdx.x;
    int w = tid >> 6, lane = tid & 63;
    int row0 = blockIdx.y * 128, col0 = blockIdx.x * 128;
    int kbase = blockIdx.z * klen;
    int wave_m = (w >> 1) * 64, wave_n = (w & 1) * 64;
    int lm = lane & 15, lq = lane >> 4;

    int srow = lane >> 3;
    int sg   = lane & 7;
    int scol = (sg ^ srow) * 8;          // swizzled source column group
    const bf16 *gA[4], *gB[4];
    bf16 *lA[4], *lB[4];
#pragma unroll
    for (int i = 0; i < 4; ++i) {
        int c = w * 4 + i;
        int row = c * 8 + srow;
        gA[i] = Ab  + (size_t)(row0 + row) * K + kbase + scol;
        gB[i] = BTb + (size_t)(col0 + row) * K + kbase + scol;
        lA[i] = sA + c * 512 + lane * 8;
        lB[i] = sB + c * 512 + lane * 8;
    }

    floatx4 acc[4][4];
#pragma unroll
    for (int mf = 0; mf < 4; ++mf)
#pragma unroll
        for (int nf = 0; nf < 4; ++nf)
            acc[mf][nf] = (floatx4){0.f, 0.f, 0.f, 0.f};

    for (int kk = 0; kk < klen; kk += 64) {
        __syncthreads();
#pragma unroll
        for (int i = 0; i < 4; ++i) {
            gld16(gA[i] + kk, lA[i]);
            gld16(gB[i] + kk, lB[i]);
        }
        __syncthreads();
#pragma unroll
        for (int ks = 0; ks < 2; ++ks) {
            short8 af[4], bfv[4];
#pragma unroll
            for (int mf = 0; mf < 4; ++mf) {
                int row = wave_m + mf * 16 + lm;
                int g = (ks * 4 + lq) ^ (row & 7);
                af[mf] = *(const short8*)&sA[row * 64 + g * 8];
            }
#pragma unroll
            for (int nf = 0; nf < 4; ++nf) {
                int row = wave_n + nf * 16 + lm;
                int g = (ks * 4 + lq) ^ (row & 7);
                bfv[nf] = *(const short8*)&sB[row * 64 + g * 8];
            }
#pragma unroll
            for (int mf = 0; mf < 4; ++mf)
#pragma unroll
                for (int nf = 0; nf < 4; ++nf)
                    acc[mf][nf] = __builtin_amdgcn_mfma_f32_16x16x32_bf16(
                        af[mf], bfv[nf], acc[mf][nf], 0, 0, 0);
        }
    }

    bf16* slice = Pb + (size_t)blockIdx.z * M * N;
#pragma unroll
    for (int mf = 0; mf < 4; ++mf) {
#pragma unroll
        for (int nf = 0; nf < 4; ++nf) {
            int gcol = col0 + wave_n + nf * 16 + lm;
#pragma unroll
            for (int r = 0; r < 4; ++r) {
                int grow = row0 + wave_m + mf * 16 + lq * 4 + r;
                slice[(size_t)grow * N + gcol] = __float2bfloat16(acc[mf][nf][r]);
            }
        }
    }
}

// ---------------- launcher ----------------

extern "C" void kernel_launch(void* const* d_in, const int* in_sizes, int n_in,
                              void* d_out, int out_size, void* d_ws, size_t ws_size,
                              hipStream_t stream) {
    const void* Xr_in = d_in[0];
    const void* Xi_in = d_in[1];
    const void* edges = d_in[2];
    const void* q     = d_in[3];
    const void* ew    = d_in[4];
    const void* Wt    = d_in[5];
    const void* bias  = d_in[6];

    char* base = (char*)d_ws;
    const size_t MB = 1024 * 1024;
    float* A      = (float*)(base);                 // 16 MB during prep (dead after build_Mpack)
    bf16*  Pb     = (bf16*)(base);                  // 16 MB: 4 bf16 partial slices (reused 3x)
    bf16*  Mpack  = (bf16*)(base + 16 * MB);        // 16 MB
    bf16*  Af     = (bf16*)(base + 32 * MB);        // 12 MB
    bf16*  BTb    = (bf16*)(base + 44 * MB);        // 8 MB
    bf16*  WT     = (bf16*)(base + 52 * MB);        // 1.5 MB
    float* rowsum = (float*)(base + 53 * MB + 512 * 1024);  // 8 KB
    float* colsum = (float*)(base + 53 * MB + 520 * 1024);  // 8 KB
    int*   flag   = (int*)  (base + 53 * MB + 528 * 1024);  // 8 B

    detect_k<<<1, 256, 0, stream>>>((const unsigned int*)q, (const unsigned int*)edges,
                                    flag, colsum);
    hipMemsetAsync(A, 0, 16 * MB, stream);

    scatter_edges_k<<<NEDGE / 256, 256, 0, stream>>>(edges, ew, A, flag);
    row_sums_k<<<NN, 256, 0, stream>>>(A, rowsum);
    col_sums_k<<<dim3(NN / 256, NN / 64), 256, 0, stream>>>(A, colsum);
    build_Mpack_k<<<dim3(NN / 32, NN / 32), dim3(32, 32), 0, stream>>>(
        A, rowsum, colsum, q, Mpack, flag);

    // A dead -> Pb may reuse base
    convert_X_BT_k<<<dim3(CC / 32, NN / 32), dim3(32, 32), 0, stream>>>(
        Xr_in, Xi_in, Af, BTb, flag);
    pack_WT_k<<<dim3(1536 / 32, CC / 32), dim3(32, 32), 0, stream>>>(Wt, WT, flag);

    // G1 (operand-swapped): PT[1024][2048] = XpackT @ Mpack^T, splitK=4 bf16 partials
    gemm_sk_k<<<dim3(NN / 128, 1024 / 128, 4), 256, 0, stream>>>(
        BTb, Mpack, 1024, NN, 4096, 1024, Pb);
    packPT_k<<<dim3(2048 / 32, 512 / 32), dim3(32, 32), 0, stream>>>(Pb, BTb, Af);

    // G2: P = Mpack @ Z1packT^T, splitK=4 ; Af seg2 = 2*sum(P) - X
    gemm_sk_k<<<dim3(1024 / 128, NN / 128, 4), 256, 0, stream>>>(
        Mpack, BTb, NN, 1024, 4096, 1024, Pb);
    epi2_k<<<(NN * 1024) / 256, 256, 0, stream>>>(Pb, Xr_in, Xi_in, Af, flag);

    // G3: P = Af @ WT^T (M=4096, N=512, K=1536, splitK=4) ; out = sum(P) + bias
    gemm_sk_k<<<dim3(CC / 128, 4096 / 128, 4), 256, 0, stream>>>(
        Af, WT, 4096, CC, 1536, 384, Pb);
    epi3_k<<<(4096 * CC) / 256, 256, 0, stream>>>(Pb, bias, d_out, flag);
}